// Round 7
// baseline (331.649 us; speedup 1.0000x reference)
//
#include <hip/hip_runtime.h>
#include <hip/hip_bf16.h>

// ---- problem constants ----
#define BB 2
#define SS 2048
#define DMODEL 1024
#define NHEADS 16
#define DHEAD 64
#define MTOT (BB*SS)      // 4096
#define NQKV 3072
#define QSCALE 0.18033688011112042f   // 0.125 * log2(e), folded into Q at projection

typedef short bh8 __attribute__((ext_vector_type(8)));   // 8 bf16 (4 VGPRs)
typedef float fx4 __attribute__((ext_vector_type(4)));   // MFMA accumulator

__device__ __forceinline__ short f2bs(float f) {
    __hip_bfloat16 h = __float2bfloat16(f);
    return *reinterpret_cast<short*>(&h);
}

// ---------------- prep: fp32 -> bf16 elementwise ----------------
__global__ __launch_bounds__(256) void cvt_emb(const float* __restrict__ x,
                                               short* __restrict__ y, int n) {
    int i = (blockIdx.x * 256 + threadIdx.x) * 4;
    if (i + 3 < n) {
        float4 v = *(const float4*)(x + i);
        short4 o;
        o.x = f2bs(v.x); o.y = f2bs(v.y); o.z = f2bs(v.z); o.w = f2bs(v.w);
        *(short4*)(y + i) = o;
    }
}

// ------------- prep: transpose + convert weights (1024x1024 each) -------------
__global__ __launch_bounds__(256) void transpose_w(
        const float* __restrict__ Wq, const float* __restrict__ Wk,
        const float* __restrict__ Wv, const float* __restrict__ Wo,
        short* __restrict__ Wt_qkv, short* __restrict__ Wot) {
    __shared__ float tile[64][65];
    int z = blockIdx.z;
    const float* src = (z == 0) ? Wq : (z == 1) ? Wk : (z == 2) ? Wv : Wo;
    short* dst = (z == 3) ? Wot : (Wt_qkv + (size_t)z * 1024 * 1024);
    int n0 = blockIdx.x * 64, k0 = blockIdx.y * 64;
    int tx = threadIdx.x, ty = threadIdx.y;
    for (int j = 0; j < 16; j++) {
        int r = ty + j * 4;
        tile[r][tx] = src[(size_t)(k0 + r) * 1024 + n0 + tx];
    }
    __syncthreads();
    for (int j = 0; j < 16; j++) {
        int r = ty + j * 4;
        dst[(size_t)(n0 + r) * 1024 + k0 + tx] = f2bs(tile[tx][r]);
    }
}

// ---------------- LDS-free direct GEMM: C[m][n] = sum_k A[m][k]*Bt[n][k] ----------------
// 128x128 block, 4 waves (2x2), wave tile 64x64. NO LDS, NO barriers: each wave
// loads its MFMA fragments straight from global (16B/lane, line-efficient), reg
// double-buffered with distance-1 prefetch. Per-CU working set (A+B panels,
// 16KB/block) is L1-resident; k-march window is L2-resident chip-wide.
__global__ __launch_bounds__(256) void gemm_bt(
        const short* __restrict__ A, const short* __restrict__ Bt, int mode,
        const float* __restrict__ bq, const float* __restrict__ bk,
        const float* __restrict__ bv, const float* __restrict__ bo,
        short* __restrict__ Qout, short* __restrict__ Kout,
        short* __restrict__ Vtout, float* __restrict__ Cout) {
    const int K = 1024;
    int tid = threadIdx.x;
    int m0 = blockIdx.y * 128, n0 = blockIdx.x * 128;
    int w = tid >> 6, l = tid & 63, quad = l >> 4, ln = l & 15;
    int wm = w & 1, wn = w >> 1;

    const short* pa[4];
    const short* pb[4];
    #pragma unroll
    for (int mt = 0; mt < 4; mt++)
        pa[mt] = A + (size_t)(m0 + wm * 64 + mt * 16 + ln) * K + quad * 8;
    #pragma unroll
    for (int nt = 0; nt < 4; nt++)
        pb[nt] = Bt + (size_t)(n0 + wn * 64 + nt * 16 + ln) * K + quad * 8;

    bh8 fa[2][4], fb[2][4];
    #pragma unroll
    for (int x = 0; x < 4; x++) {
        fa[0][x] = *(const bh8*)(pa[x]);
        fb[0][x] = *(const bh8*)(pb[x]);
    }

    fx4 acc[4][4] = {};
    // unroll-by-2 ping-pong; k of iter it = it*32 + quad*8
    for (int it = 0; it < 32; it += 2) {
        {   // prefetch it+1 into buf1
            int k0 = (it + 1) * 32;
            #pragma unroll
            for (int x = 0; x < 4; x++) {
                fa[1][x] = *(const bh8*)(pa[x] + k0);
                fb[1][x] = *(const bh8*)(pb[x] + k0);
            }
        }
        #pragma unroll
        for (int mt = 0; mt < 4; mt++)
            #pragma unroll
            for (int nt = 0; nt < 4; nt++)
                acc[mt][nt] = __builtin_amdgcn_mfma_f32_16x16x32_bf16(fa[0][mt], fb[0][nt], acc[mt][nt], 0, 0, 0);
        if (it < 30) {   // prefetch it+2 into buf0
            int k0 = (it + 2) * 32;
            #pragma unroll
            for (int x = 0; x < 4; x++) {
                fa[0][x] = *(const bh8*)(pa[x] + k0);
                fb[0][x] = *(const bh8*)(pb[x] + k0);
            }
        }
        #pragma unroll
        for (int mt = 0; mt < 4; mt++)
            #pragma unroll
            for (int nt = 0; nt < 4; nt++)
                acc[mt][nt] = __builtin_amdgcn_mfma_f32_16x16x32_bf16(fa[1][mt], fb[1][nt], acc[mt][nt], 0, 0, 0);
    }

    #pragma unroll
    for (int mt = 0; mt < 4; mt++) {
        #pragma unroll
        for (int nt = 0; nt < 4; nt++) {
            int n = n0 + wn * 64 + nt * 16 + ln;
            int mbase = m0 + wm * 64 + mt * 16 + quad * 4;
            #pragma unroll
            for (int r = 0; r < 4; r++) {
                float v = acc[mt][nt][r];
                int m = mbase + r;
                if (mode == 0) {
                    int which = n >> 10, nn = n & 1023, h = nn >> 6, d = nn & 63;
                    float bias = (which == 0) ? bq[nn] : (which == 1) ? bk[nn] : bv[nn];
                    v += bias;
                    int b = m >> 11, s = m & 2047;
                    if (which == 0)
                        Qout[(((size_t)(b * 16 + h) * 2048) + s) * 64 + d] = f2bs(v * QSCALE);
                    else if (which == 1)
                        Kout[(((size_t)(b * 16 + h) * 2048) + s) * 64 + d] = f2bs(v);
                    else
                        Vtout[((size_t)(b * 16 + h) * 64 + d) * 2048 + s] = f2bs(v);
                } else {
                    Cout[(size_t)m * 1024 + n] = v + bo[n];
                }
            }
        }
    }
}

// ---------------- flash attention v4: split-K-2, no-max softmax ----------------
// grid (16, 32, 2). Block: 4 waves x 32 q-rows = 128 q; key range [z*1024,+1024).
// Partials are linear (no max): O_part = sum exp2(s)*V, l_part = sum exp2(s).
// Single-buffered K/V (reg prefetch, 2 raw barriers/iter) -> LDS ~33KB -> 4 blocks/CU.
__global__ __launch_bounds__(256, 4) void flash_attn(
        const short* __restrict__ Q, const short* __restrict__ Kg,
        const short* __restrict__ Vt,
        float* __restrict__ O0, float* __restrict__ O1,
        float* __restrict__ L0, float* __restrict__ L1) {
    __shared__ __align__(16) short Ks[64 * 64];      // [key][d] swizzled
    __shared__ __align__(16) short Vs[64 * 64];      // [d][key] swizzled
    __shared__ __align__(16) short Ps[4][32 * 68];   // per-wave P buffer / fp32 transpose

    int tid = threadIdx.x;
    int w = tid >> 6, l = tid & 63, quad = l >> 4, ln = l & 15;
    int bh = blockIdx.y, z = blockIdx.z;
    int qblk = blockIdx.x * 128 + w * 32;
    const short* Qb = Q  + (size_t)bh * 2048 * 64;
    const short* Kb = Kg + (size_t)bh * 2048 * 64 + (size_t)z * 1024 * 64;
    const short* Vb = Vt + (size_t)bh * 64 * 2048 + z * 1024;
    float* Op = z ? O1 : O0;
    float* Lp = z ? L1 : L0;
    int swz = ln & 7;

    // Q fragments (B-operand)
    bh8 qf[2][2];
    #pragma unroll
    for (int qt = 0; qt < 2; qt++)
        #pragma unroll
        for (int c = 0; c < 2; c++)
            qf[qt][c] = *(const bh8*)&Qb[(size_t)(qblk + qt * 16 + ln) * 64 + c * 32 + quad * 8];

    // staging: thread -> row srow, pairs sp0 and sp0+4 (pair = 8 shorts = 16B)
    int srow = tid >> 2, sp0 = tid & 3;
    int kw0 = srow * 64 + ((sp0 ^ (srow & 7)) * 8);
    int kw1 = srow * 64 + (((sp0 + 4) ^ (srow & 7)) * 8);
    const short* gK = Kb + (size_t)srow * 64;
    const short* gV = Vb + (size_t)srow * 2048;

    {   // prologue: stage tile 0
        uint4 a = *(const uint4*)(gK + sp0 * 8);
        uint4 bb = *(const uint4*)(gK + (sp0 + 4) * 8);
        uint4 c = *(const uint4*)(gV + sp0 * 8);
        uint4 d = *(const uint4*)(gV + (sp0 + 4) * 8);
        *(uint4*)&Ks[kw0] = a; *(uint4*)&Ks[kw1] = bb;
        *(uint4*)&Vs[kw0] = c; *(uint4*)&Vs[kw1] = d;
    }
    asm volatile("s_waitcnt lgkmcnt(0)\n\ts_barrier" ::: "memory");

    fx4 o[2][4] = {};
    float lpart[2] = {0.f, 0.f};

    for (int it = 0; it < 16; ++it) {
        uint4 ra, rb, rc, rd;
        bool pre = (it < 15);
        if (pre) {   // prefetch next tile into regs; latency hidden by compute
            const short* gk = gK + (size_t)(it + 1) * 4096;
            const short* gv = gV + (size_t)(it + 1) * 64;
            ra = *(const uint4*)(gk + sp0 * 8);
            rb = *(const uint4*)(gk + (sp0 + 4) * 8);
            rc = *(const uint4*)(gv + sp0 * 8);
            rd = *(const uint4*)(gv + (sp0 + 4) * 8);
        }

        // S^T[key][q] = K * Q^T
        fx4 s[2][4] = {};
        #pragma unroll
        for (int mt = 0; mt < 4; mt++) {
            bh8 kf0 = *(const bh8*)&Ks[(mt * 16 + ln) * 64 + ((quad ^ swz) * 8)];
            bh8 kf1 = *(const bh8*)&Ks[(mt * 16 + ln) * 64 + (((quad + 4) ^ swz) * 8)];
            #pragma unroll
            for (int qt = 0; qt < 2; qt++) {
                s[qt][mt] = __builtin_amdgcn_mfma_f32_16x16x32_bf16(kf0, qf[qt][0], s[qt][mt], 0, 0, 0);
                s[qt][mt] = __builtin_amdgcn_mfma_f32_16x16x32_bf16(kf1, qf[qt][1], s[qt][mt], 0, 0, 0);
            }
        }

        // P = exp2(S) (raw v_exp_f32 — args are bounded, no range fixup needed)
        #pragma unroll
        for (int qt = 0; qt < 2; qt++) {
            #pragma unroll
            for (int mt = 0; mt < 4; mt++) {
                float p0 = __builtin_amdgcn_exp2f(s[qt][mt][0]);
                float p1 = __builtin_amdgcn_exp2f(s[qt][mt][1]);
                float p2 = __builtin_amdgcn_exp2f(s[qt][mt][2]);
                float p3 = __builtin_amdgcn_exp2f(s[qt][mt][3]);
                lpart[qt] += (p0 + p1) + (p2 + p3);
                union { __hip_bfloat162 h2[2]; short4 s4; } u;
                u.h2[0] = __float22bfloat162_rn(make_float2(p0, p1));
                u.h2[1] = __float22bfloat162_rn(make_float2(p2, p3));
                *(short4*)&Ps[w][(qt * 16 + ln) * 64 +
                                 (((mt * 2 + (quad >> 1)) ^ swz) * 8) + (quad & 1) * 4] = u.s4;
            }
        }
        asm volatile("s_waitcnt lgkmcnt(0)" ::: "memory");

        // O^T += V^T * P^T
        #pragma unroll
        for (int c2 = 0; c2 < 2; c2++) {
            bh8 pf0 = *(const bh8*)&Ps[w][(0 * 16 + ln) * 64 + (((c2 * 4 + quad) ^ swz) * 8)];
            bh8 pf1 = *(const bh8*)&Ps[w][(1 * 16 + ln) * 64 + (((c2 * 4 + quad) ^ swz) * 8)];
            #pragma unroll
            for (int dt = 0; dt < 4; dt++) {
                bh8 vf = *(const bh8*)&Vs[(dt * 16 + ln) * 64 + (((c2 * 4 + quad) ^ swz) * 8)];
                o[0][dt] = __builtin_amdgcn_mfma_f32_16x16x32_bf16(vf, pf0, o[0][dt], 0, 0, 0);
                o[1][dt] = __builtin_amdgcn_mfma_f32_16x16x32_bf16(vf, pf1, o[1][dt], 0, 0, 0);
            }
        }

        asm volatile("s_barrier" ::: "memory");   // all waves done reading Ks/Vs
        if (pre) {
            *(uint4*)&Ks[kw0] = ra; *(uint4*)&Ks[kw1] = rb;
            *(uint4*)&Vs[kw0] = rc; *(uint4*)&Vs[kw1] = rd;
        }
        asm volatile("s_waitcnt lgkmcnt(0)\n\ts_barrier" ::: "memory");
    }

    // epilogue: fp32 partials O^T -> O via per-wave LDS transpose, + l partials.
    float* PsF = (float*)&Ps[w][0];   // 16 rows x 68-float stride
    int row = l >> 2, seg = l & 3;
    #pragma unroll
    for (int qt = 0; qt < 2; qt++) {
        #pragma unroll
        for (int dt = 0; dt < 4; dt++)
            *(fx4*)&PsF[ln * 68 + dt * 16 + quad * 4] = o[qt][dt];
        asm volatile("s_waitcnt lgkmcnt(0)" ::: "memory");
        float* orow = &Op[((size_t)bh * 2048 + qblk + qt * 16 + row) * 64];
        #pragma unroll
        for (int j = 0; j < 4; j++) {
            fx4 v = *(fx4*)&PsF[row * 68 + seg * 16 + j * 4];
            *(fx4*)&orow[seg * 16 + j * 4] = v;
        }
        asm volatile("s_waitcnt lgkmcnt(0)" ::: "memory");
        float lr = lpart[qt];
        lr += __shfl_xor(lr, 16);
        lr += __shfl_xor(lr, 32);
        if (l < 16) Lp[(size_t)bh * 2048 + qblk + qt * 16 + l] = lr;
    }
}

// ---------------- combine: Ctx = (O0+O1)/(L0+L1), bf16 ----------------
__global__ __launch_bounds__(256) void combine(
        const float* __restrict__ O0, const float* __restrict__ O1,
        const float* __restrict__ L0, const float* __restrict__ L1,
        short* __restrict__ Ctx) {
    int t = blockIdx.x * 256 + threadIdx.x;        // 524288 threads, 8 floats each
    size_t base = (size_t)t * 8;
    int bhq = t >> 3;
    int d = (t & 7) * 8;
    int bh = bhq >> 11, q = bhq & 2047;
    int b = bh >> 4, h = bh & 15;
    float inv = 1.0f / (L0[bhq] + L1[bhq]);
    float4 a0 = *(const float4*)(O0 + base);
    float4 a1 = *(const float4*)(O0 + base + 4);
    float4 c0 = *(const float4*)(O1 + base);
    float4 c1 = *(const float4*)(O1 + base + 4);
    union { short s[8]; bh8 v; } o;
    o.s[0] = f2bs((a0.x + c0.x) * inv); o.s[1] = f2bs((a0.y + c0.y) * inv);
    o.s[2] = f2bs((a0.z + c0.z) * inv); o.s[3] = f2bs((a0.w + c0.w) * inv);
    o.s[4] = f2bs((a1.x + c1.x) * inv); o.s[5] = f2bs((a1.y + c1.y) * inv);
    o.s[6] = f2bs((a1.z + c1.z) * inv); o.s[7] = f2bs((a1.w + c1.w) * inv);
    *(bh8*)&Ctx[((size_t)(b * 2048 + q)) * 1024 + h * 64 + d] = o.v;
}

extern "C" void kernel_launch(void* const* d_in, const int* in_sizes, int n_in,
                              void* d_out, int out_size, void* d_ws, size_t ws_size,
                              hipStream_t stream) {
    const float* emb = (const float*)d_in[0];
    const float* Wq  = (const float*)d_in[1];
    const float* bq  = (const float*)d_in[2];
    const float* Wk  = (const float*)d_in[3];
    const float* bk  = (const float*)d_in[4];
    const float* Wv  = (const float*)d_in[5];
    const float* bv  = (const float*)d_in[6];
    const float* Wo  = (const float*)d_in[7];
    const float* bo  = (const float*)d_in[8];

    char* ws = (char*)d_ws;
    const size_t MB = 1024 * 1024;
    short* Xbf  = (short*)(ws + 0);
    short* Wt   = (short*)(ws + 8 * MB);
    float* Op1  = (float*)(ws + 0);          // flash partial z=1 (reuses Xbf/Wt)
    short* Wot  = (short*)(ws + 17 * MB);
    short* Qb   = (short*)(ws + 19 * MB);    // pre-scaled by QSCALE
    short* Ctx  = (short*)(ws + 19 * MB);    // overlays Qb (combine after flash)
    short* Kb   = (short*)(ws + 27 * MB);
    short* Vtb  = (short*)(ws + 35 * MB);    // [B,H,Dh,S]
    float* L0   = (float*)(ws + 43 * MB);
    float* L1   = (float*)(ws + 43 * MB + 256 * 1024);
    float* Op0  = (float*)d_out;             // flash partial z=0 (d_out as scratch,
                                             // fully overwritten by final gemm)

    cvt_emb<<<4096, 256, 0, stream>>>(emb, Xbf, MTOT * DMODEL);
    transpose_w<<<dim3(16, 16, 4), dim3(64, 4), 0, stream>>>(Wq, Wk, Wv, Wo, Wt, Wot);
    gemm_bt<<<dim3(24, 32), 256, 0, stream>>>(Xbf, Wt, 0,
                                              bq, bk, bv, nullptr,
                                              Qb, Kb, Vtb, nullptr);
    flash_attn<<<dim3(16, 32, 2), 256, 0, stream>>>(Qb, Kb, Vtb, Op0, Op1, L0, L1);
    combine<<<2048, 256, 0, stream>>>(Op0, Op1, L0, L1, Ctx);
    gemm_bt<<<dim3(8, 32), 256, 0, stream>>>(Ctx, Wot, 1,
                                             nullptr, nullptr, nullptr, bo,
                                             nullptr, nullptr, nullptr, (float*)d_out);
}

// Round 8
// 207.660 us; speedup vs baseline: 1.5971x; 1.5971x over previous
//
#include <hip/hip_runtime.h>
#include <hip/hip_bf16.h>

// ---- problem constants ----
#define BB 2
#define SS 2048
#define DMODEL 1024
#define NHEADS 16
#define DHEAD 64
#define MTOT (BB*SS)      // 4096
#define NQKV 3072
#define QSCALE 0.18033688011112042f   // 0.125 * log2(e), folded into Q at projection

typedef short bh8 __attribute__((ext_vector_type(8)));   // 8 bf16 (4 VGPRs)
typedef float fx4 __attribute__((ext_vector_type(4)));   // MFMA accumulator

__device__ __forceinline__ short f2bs(float f) {
    __hip_bfloat16 h = __float2bfloat16(f);
    return *reinterpret_cast<short*>(&h);
}

// async global->LDS, 16B per lane. LDS dest wave-uniform base + lane*16.
__device__ __forceinline__ void gload_lds16(const short* g, short* l) {
    __builtin_amdgcn_global_load_lds(
        (const __attribute__((address_space(1))) unsigned int*)g,
        (__attribute__((address_space(3))) unsigned int*)l, 16, 0, 0);
}

// ---------------- prep: fp32 -> bf16 elementwise ----------------
__global__ __launch_bounds__(256) void cvt_emb(const float* __restrict__ x,
                                               short* __restrict__ y, int n) {
    int i = (blockIdx.x * 256 + threadIdx.x) * 4;
    if (i + 3 < n) {
        float4 v = *(const float4*)(x + i);
        short4 o;
        o.x = f2bs(v.x); o.y = f2bs(v.y); o.z = f2bs(v.z); o.w = f2bs(v.w);
        *(short4*)(y + i) = o;
    }
}

// ------------- prep: transpose + convert weights (1024x1024 each) -------------
__global__ __launch_bounds__(256) void transpose_w(
        const float* __restrict__ Wq, const float* __restrict__ Wk,
        const float* __restrict__ Wv, const float* __restrict__ Wo,
        short* __restrict__ Wt_qkv, short* __restrict__ Wot) {
    __shared__ float tile[64][65];
    int z = blockIdx.z;
    const float* src = (z == 0) ? Wq : (z == 1) ? Wk : (z == 2) ? Wv : Wo;
    short* dst = (z == 3) ? Wot : (Wt_qkv + (size_t)z * 1024 * 1024);
    int n0 = blockIdx.x * 64, k0 = blockIdx.y * 64;
    int tx = threadIdx.x, ty = threadIdx.y;
    for (int j = 0; j < 16; j++) {
        int r = ty + j * 4;
        tile[r][tx] = src[(size_t)(k0 + r) * 1024 + n0 + tx];
    }
    __syncthreads();
    for (int j = 0; j < 16; j++) {
        int r = ty + j * 4;
        dst[(size_t)(n0 + r) * 1024 + k0 + tx] = f2bs(tile[tx][r]);
    }
}

// ---------------- bt-GEMM (templated): C[m][n] = sum_k A[m][k]*Bt[n][k] ----------------
// BMxBN block, 4 waves (2x2), 3-stage global_load_lds pipeline with raw
// s_waitcnt vmcnt(CPW)+s_barrier (never vmcnt(0) mid-loop). XCD-aware 1D grid
// decode: XCD owns an M-strip so its A panel stays L2-hot; B streams once/XCD.
template<int BM, int BN, int NN, int MODE>
__global__ __launch_bounds__(256) void gemm_bt_t(
        const short* __restrict__ A, const short* __restrict__ Bt,
        const float* __restrict__ bq, const float* __restrict__ bk,
        const float* __restrict__ bv, const float* __restrict__ bo,
        short* __restrict__ Qout, short* __restrict__ Kout,
        short* __restrict__ Vtout, float* __restrict__ Cout) {
    const int K = 1024;
    constexpr int ROWS = BM + BN;        // combined A+B panel rows per k-tile
    constexpr int CPW  = ROWS / 64;      // 16-row staging chunks per wave
    constexpr int MBK  = MTOT / BM;      // m-blocks
    constexpr int STRIP = MBK / 8;       // m-tiles per XCD strip
    constexpr int MT = BM / 32, NT = BN / 32;
    __shared__ __align__(16) short S[3][ROWS * 32];

    int tid = threadIdx.x;
    int w = tid >> 6, l = tid & 63, quad = l >> 4, ln = l & 15;
    int wm = w & 1, wn = w >> 1;

    // XCD-aware decode: id%8 ~ XCD; XCD owns M-strip [xcd*STRIP, xcd*STRIP+STRIP)
    int id = blockIdx.x;
    int xcd = id & 7, local = id >> 3;
    int mi = xcd * STRIP + (local % STRIP);
    int ni = local / STRIP;
    int m0 = mi * BM, n0 = ni * BN;

    // staging chunk map: chunk c = w*CPW+j covers panel rows [c*16, c*16+16);
    // panel rows [0,BM) = A tile rows, [BM,ROWS) = B tile rows.
    const short* gsrc[CPW];
    int loff[CPW];
    #pragma unroll
    for (int j = 0; j < CPW; j++) {
        int r0 = (w * CPW + j) * 16;
        int row = r0 + (l >> 2);
        gsrc[j] = (r0 < BM ? A + (size_t)(m0 + row) * K
                           : Bt + (size_t)(n0 + row - BM) * K) + (l & 3) * 8;
        loff[j] = r0 * 32;
    }

    short *sC = &S[0][0], *sN = &S[1][0], *sN2 = &S[2][0];
    #pragma unroll
    for (int j = 0; j < CPW; j++) gload_lds16(gsrc[j], sC + loff[j]);
    #pragma unroll
    for (int j = 0; j < CPW; j++) gload_lds16(gsrc[j] + 32, sN + loff[j]);

    fx4 acc[MT][NT] = {};
    for (int it = 0; it < 32; ++it) {
        if (it < 31) {
            if constexpr (CPW == 4)
                asm volatile("s_waitcnt vmcnt(4)\n\ts_barrier" ::: "memory");
            else
                asm volatile("s_waitcnt vmcnt(3)\n\ts_barrier" ::: "memory");
        } else {
            asm volatile("s_waitcnt vmcnt(0)\n\ts_barrier" ::: "memory");
        }
        if (it < 30) {
            int k0 = (it + 2) * 32;
            #pragma unroll
            for (int j = 0; j < CPW; j++) gload_lds16(gsrc[j] + k0, sN2 + loff[j]);
        }
        bh8 af[MT], bf[NT];
        #pragma unroll
        for (int mt = 0; mt < MT; mt++)
            af[mt] = *(const bh8*)&sC[(wm * (BM / 2) + mt * 16 + ln) * 32 + quad * 8];
        #pragma unroll
        for (int nt = 0; nt < NT; nt++)
            bf[nt] = *(const bh8*)&sC[(BM + wn * (BN / 2) + nt * 16 + ln) * 32 + quad * 8];
        #pragma unroll
        for (int mt = 0; mt < MT; mt++)
            #pragma unroll
            for (int nt = 0; nt < NT; nt++)
                acc[mt][nt] = __builtin_amdgcn_mfma_f32_16x16x32_bf16(af[mt], bf[nt], acc[mt][nt], 0, 0, 0);
        short* t;
        t = sC; sC = sN; sN = sN2; sN2 = t;
    }

    #pragma unroll
    for (int mt = 0; mt < MT; mt++) {
        #pragma unroll
        for (int nt = 0; nt < NT; nt++) {
            int n = n0 + wn * (BN / 2) + nt * 16 + ln;
            int mbase = m0 + wm * (BM / 2) + mt * 16 + quad * 4;
            #pragma unroll
            for (int r = 0; r < 4; r++) {
                float v = acc[mt][nt][r];
                int m = mbase + r;
                if constexpr (MODE == 0) {
                    int which = n >> 10, nn = n & 1023, h = nn >> 6, d = nn & 63;
                    float bias = (which == 0) ? bq[nn] : (which == 1) ? bk[nn] : bv[nn];
                    v += bias;
                    int b = m >> 11, s = m & 2047;
                    if (which == 0)
                        Qout[(((size_t)(b * 16 + h) * 2048) + s) * 64 + d] = f2bs(v * QSCALE);
                    else if (which == 1)
                        Kout[(((size_t)(b * 16 + h) * 2048) + s) * 64 + d] = f2bs(v);
                    else
                        Vtout[((size_t)(b * 16 + h) * 64 + d) * 2048 + s] = f2bs(v);
                } else {
                    Cout[(size_t)m * 1024 + n] = v + bo[n];
                }
            }
        }
    }
}

// ---------------- flash attention: split-K-2, no-max softmax, XCD swizzle ----------------
// 1D grid 1024. XCD owns 4 bh -> K/V halves (2MB) stay L2-resident.
// Partials are linear (no max): O_part = sum exp2(s)*V, l_part = sum exp2(s).
__global__ __launch_bounds__(256, 4) void flash_attn(
        const short* __restrict__ Q, const short* __restrict__ Kg,
        const short* __restrict__ Vt,
        float* __restrict__ O0, float* __restrict__ O1,
        float* __restrict__ L0, float* __restrict__ L1) {
    __shared__ __align__(16) short Ks[64 * 64];      // [key][d] swizzled
    __shared__ __align__(16) short Vs[64 * 64];      // [d][key] swizzled
    __shared__ __align__(16) short Ps[4][32 * 68];   // per-wave P buffer / fp32 transpose

    int tid = threadIdx.x;
    int w = tid >> 6, l = tid & 63, quad = l >> 4, ln = l & 15;
    // XCD-aware decode: 4 bh per XCD
    int id = blockIdx.x;
    int xcd = id & 7, local = id >> 3;           // local 0..127
    int bh = xcd * 4 + (local & 3);
    int t = local >> 2;                          // 0..31
    int qx = t & 15, z = t >> 4;
    int qblk = qx * 128 + w * 32;
    const short* Qb = Q  + (size_t)bh * 2048 * 64;
    const short* Kb = Kg + (size_t)bh * 2048 * 64 + (size_t)z * 1024 * 64;
    const short* Vb = Vt + (size_t)bh * 64 * 2048 + z * 1024;
    float* Op = z ? O1 : O0;
    float* Lp = z ? L1 : L0;
    int swz = ln & 7;

    // Q fragments (B-operand)
    bh8 qf[2][2];
    #pragma unroll
    for (int qt = 0; qt < 2; qt++)
        #pragma unroll
        for (int c = 0; c < 2; c++)
            qf[qt][c] = *(const bh8*)&Qb[(size_t)(qblk + qt * 16 + ln) * 64 + c * 32 + quad * 8];

    // staging: thread -> row srow, pairs sp0 and sp0+4 (pair = 8 shorts = 16B)
    int srow = tid >> 2, sp0 = tid & 3;
    int kw0 = srow * 64 + ((sp0 ^ (srow & 7)) * 8);
    int kw1 = srow * 64 + (((sp0 + 4) ^ (srow & 7)) * 8);
    const short* gK = Kb + (size_t)srow * 64;
    const short* gV = Vb + (size_t)srow * 2048;

    {   // prologue: stage tile 0
        uint4 a = *(const uint4*)(gK + sp0 * 8);
        uint4 bb = *(const uint4*)(gK + (sp0 + 4) * 8);
        uint4 c = *(const uint4*)(gV + sp0 * 8);
        uint4 d = *(const uint4*)(gV + (sp0 + 4) * 8);
        *(uint4*)&Ks[kw0] = a; *(uint4*)&Ks[kw1] = bb;
        *(uint4*)&Vs[kw0] = c; *(uint4*)&Vs[kw1] = d;
    }
    asm volatile("s_waitcnt lgkmcnt(0)\n\ts_barrier" ::: "memory");

    fx4 o[2][4] = {};
    float lpart[2] = {0.f, 0.f};

    for (int it = 0; it < 16; ++it) {
        uint4 ra, rb, rc, rd;
        bool pre = (it < 15);
        if (pre) {   // prefetch next tile into regs; latency hidden by compute
            const short* gk = gK + (size_t)(it + 1) * 4096;
            const short* gv = gV + (size_t)(it + 1) * 64;
            ra = *(const uint4*)(gk + sp0 * 8);
            rb = *(const uint4*)(gk + (sp0 + 4) * 8);
            rc = *(const uint4*)(gv + sp0 * 8);
            rd = *(const uint4*)(gv + (sp0 + 4) * 8);
        }

        // S^T[key][q] = K * Q^T
        fx4 s[2][4] = {};
        #pragma unroll
        for (int mt = 0; mt < 4; mt++) {
            bh8 kf0 = *(const bh8*)&Ks[(mt * 16 + ln) * 64 + ((quad ^ swz) * 8)];
            bh8 kf1 = *(const bh8*)&Ks[(mt * 16 + ln) * 64 + (((quad + 4) ^ swz) * 8)];
            #pragma unroll
            for (int qt = 0; qt < 2; qt++) {
                s[qt][mt] = __builtin_amdgcn_mfma_f32_16x16x32_bf16(kf0, qf[qt][0], s[qt][mt], 0, 0, 0);
                s[qt][mt] = __builtin_amdgcn_mfma_f32_16x16x32_bf16(kf1, qf[qt][1], s[qt][mt], 0, 0, 0);
            }
        }

        // P = exp2(S) (raw v_exp_f32 — args bounded, no range fixup needed)
        #pragma unroll
        for (int qt = 0; qt < 2; qt++) {
            #pragma unroll
            for (int mt = 0; mt < 4; mt++) {
                float p0 = __builtin_amdgcn_exp2f(s[qt][mt][0]);
                float p1 = __builtin_amdgcn_exp2f(s[qt][mt][1]);
                float p2 = __builtin_amdgcn_exp2f(s[qt][mt][2]);
                float p3 = __builtin_amdgcn_exp2f(s[qt][mt][3]);
                lpart[qt] += (p0 + p1) + (p2 + p3);
                union { __hip_bfloat162 h2[2]; short4 s4; } u;
                u.h2[0] = __float22bfloat162_rn(make_float2(p0, p1));
                u.h2[1] = __float22bfloat162_rn(make_float2(p2, p3));
                *(short4*)&Ps[w][(qt * 16 + ln) * 64 +
                                 (((mt * 2 + (quad >> 1)) ^ swz) * 8) + (quad & 1) * 4] = u.s4;
            }
        }
        asm volatile("s_waitcnt lgkmcnt(0)" ::: "memory");

        // O^T += V^T * P^T
        #pragma unroll
        for (int c2 = 0; c2 < 2; c2++) {
            bh8 pf0 = *(const bh8*)&Ps[w][(0 * 16 + ln) * 64 + (((c2 * 4 + quad) ^ swz) * 8)];
            bh8 pf1 = *(const bh8*)&Ps[w][(1 * 16 + ln) * 64 + (((c2 * 4 + quad) ^ swz) * 8)];
            #pragma unroll
            for (int dt = 0; dt < 4; dt++) {
                bh8 vf = *(const bh8*)&Vs[(dt * 16 + ln) * 64 + (((c2 * 4 + quad) ^ swz) * 8)];
                o[0][dt] = __builtin_amdgcn_mfma_f32_16x16x32_bf16(vf, pf0, o[0][dt], 0, 0, 0);
                o[1][dt] = __builtin_amdgcn_mfma_f32_16x16x32_bf16(vf, pf1, o[1][dt], 0, 0, 0);
            }
        }

        asm volatile("s_barrier" ::: "memory");   // all waves done reading Ks/Vs
        if (pre) {
            *(uint4*)&Ks[kw0] = ra; *(uint4*)&Ks[kw1] = rb;
            *(uint4*)&Vs[kw0] = rc; *(uint4*)&Vs[kw1] = rd;
        }
        asm volatile("s_waitcnt lgkmcnt(0)\n\ts_barrier" ::: "memory");
    }

    // epilogue: fp32 partials O^T -> O via per-wave LDS transpose, + l partials.
    float* PsF = (float*)&Ps[w][0];   // 16 rows x 68-float stride
    int row = l >> 2, seg = l & 3;
    #pragma unroll
    for (int qt = 0; qt < 2; qt++) {
        #pragma unroll
        for (int dt = 0; dt < 4; dt++)
            *(fx4*)&PsF[ln * 68 + dt * 16 + quad * 4] = o[qt][dt];
        asm volatile("s_waitcnt lgkmcnt(0)" ::: "memory");
        float* orow = &Op[((size_t)bh * 2048 + qblk + qt * 16 + row) * 64];
        #pragma unroll
        for (int j = 0; j < 4; j++) {
            fx4 v = *(fx4*)&PsF[row * 68 + seg * 16 + j * 4];
            *(fx4*)&orow[seg * 16 + j * 4] = v;
        }
        asm volatile("s_waitcnt lgkmcnt(0)" ::: "memory");
        float lr = lpart[qt];
        lr += __shfl_xor(lr, 16);
        lr += __shfl_xor(lr, 32);
        if (l < 16) Lp[(size_t)bh * 2048 + qblk + qt * 16 + l] = lr;
    }
}

// ---------------- combine: Ctx = (O0+O1)/(L0+L1), bf16 ----------------
__global__ __launch_bounds__(256) void combine(
        const float* __restrict__ O0, const float* __restrict__ O1,
        const float* __restrict__ L0, const float* __restrict__ L1,
        short* __restrict__ Ctx) {
    int t = blockIdx.x * 256 + threadIdx.x;        // 524288 threads, 8 floats each
    size_t base = (size_t)t * 8;
    int bhq = t >> 3;
    int d = (t & 7) * 8;
    int bh = bhq >> 11, q = bhq & 2047;
    int b = bh >> 4, h = bh & 15;
    float inv = 1.0f / (L0[bhq] + L1[bhq]);
    float4 a0 = *(const float4*)(O0 + base);
    float4 a1 = *(const float4*)(O0 + base + 4);
    float4 c0 = *(const float4*)(O1 + base);
    float4 c1 = *(const float4*)(O1 + base + 4);
    union { short s[8]; bh8 v; } o;
    o.s[0] = f2bs((a0.x + c0.x) * inv); o.s[1] = f2bs((a0.y + c0.y) * inv);
    o.s[2] = f2bs((a0.z + c0.z) * inv); o.s[3] = f2bs((a0.w + c0.w) * inv);
    o.s[4] = f2bs((a1.x + c1.x) * inv); o.s[5] = f2bs((a1.y + c1.y) * inv);
    o.s[6] = f2bs((a1.z + c1.z) * inv); o.s[7] = f2bs((a1.w + c1.w) * inv);
    *(bh8*)&Ctx[((size_t)(b * 2048 + q)) * 1024 + h * 64 + d] = o.v;
}

extern "C" void kernel_launch(void* const* d_in, const int* in_sizes, int n_in,
                              void* d_out, int out_size, void* d_ws, size_t ws_size,
                              hipStream_t stream) {
    const float* emb = (const float*)d_in[0];
    const float* Wq  = (const float*)d_in[1];
    const float* bq  = (const float*)d_in[2];
    const float* Wk  = (const float*)d_in[3];
    const float* bk  = (const float*)d_in[4];
    const float* Wv  = (const float*)d_in[5];
    const float* bv  = (const float*)d_in[6];
    const float* Wo  = (const float*)d_in[7];
    const float* bo  = (const float*)d_in[8];

    char* ws = (char*)d_ws;
    const size_t MB = 1024 * 1024;
    short* Xbf  = (short*)(ws + 0);
    short* Wt   = (short*)(ws + 8 * MB);
    float* Op1  = (float*)(ws + 0);          // flash partial z=1 (reuses Xbf/Wt)
    short* Wot  = (short*)(ws + 17 * MB);
    short* Qb   = (short*)(ws + 19 * MB);    // pre-scaled by QSCALE
    short* Ctx  = (short*)(ws + 19 * MB);    // overlays Qb (combine after flash)
    short* Kb   = (short*)(ws + 27 * MB);
    short* Vtb  = (short*)(ws + 35 * MB);    // [B,H,Dh,S]
    float* L0   = (float*)(ws + 43 * MB);
    float* L1   = (float*)(ws + 43 * MB + 256 * 1024);
    float* Op0  = (float*)d_out;             // flash partial z=0 (d_out as scratch,
                                             // fully overwritten by final gemm)

    cvt_emb<<<4096, 256, 0, stream>>>(emb, Xbf, MTOT * DMODEL);
    transpose_w<<<dim3(16, 16, 4), dim3(64, 4), 0, stream>>>(Wq, Wk, Wv, Wo, Wt, Wot);
    // QKV projection: 128x128 tiles, 32x24 = 768 blocks, XCD-swizzled
    gemm_bt_t<128, 128, NQKV, 0><<<768, 256, 0, stream>>>(
        Xbf, Wt, bq, bk, bv, nullptr, Qb, Kb, Vtb, nullptr);
    flash_attn<<<1024, 256, 0, stream>>>(Qb, Kb, Vtb, Op0, Op1, L0, L1);
    combine<<<2048, 256, 0, stream>>>(Op0, Op1, L0, L1, Ctx);
    // output projection: 64x128 tiles, 64x8 = 512 blocks, XCD-swizzled
    gemm_bt_t<64, 128, DMODEL, 1><<<512, 256, 0, stream>>>(
        Ctx, Wot, nullptr, nullptr, nullptr, bo, nullptr, nullptr, nullptr, (float*)d_out);
}